// Round 19
// baseline (62.068 us; speedup 1.0000x reference)
//
#include <hip/hip_runtime.h>

#define NIN 784
#define WIDTH 1024
#define HALF 512
#define DEPTH 8
#define BDEPTH 10
#define BATCH 4096
#define SPLINE_DIM 20
#define NQ 18   // knot intervals [t_m, t_m+1), m = 2..19
#define LSTRIDE 8192   // float2 per layer table (64 KB)

typedef __attribute__((ext_vector_type(2))) float f32x2;

// Clamped knot vector T[23]: [-8]*3, +-2^k/32 ladder, 0, [8]*3
__device__ float d_T[23] = {
  -8.f, -8.f, -8.f, -4.f, -2.f, -1.f, -0.5f, -0.25f, -0.125f, -0.0625f,
  -0.03125f, 0.f, 0.03125f, 0.0625f, 0.125f, 0.25f, 0.5f, 1.f, 2.f, 4.f,
  8.f, 8.f, 8.f };

// ---------------------------------------------------------------------------
// Prep kernel (IDENTICAL to validated R17). cs layout per layer (8192 f2):
//   tbl0 [0,1024):    float4[512]  steps 0,1 packed
//   tbl1 [1024,2048): float4[512]  steps 2,3 packed
//   LP p [2048+p*2048): float4[1024] steps 4+2p,5+2p per slot
//     -> float4 bases: LP0=1024, LP1=2048, LP2=3072   (R18 bug: used 1536/2048)
// qt quadratic spline unchanged (validated R3+).
// ---------------------------------------------------------------------------
__global__ void prep_kernel(const float* __restrict__ bp,
                            const float* __restrict__ sc,
                            float2* __restrict__ cs,
                            float4* __restrict__ qt) {
  int gid = blockIdx.x * 256 + threadIdx.x;
  if (gid < DEPTH * BDEPTH * 1024) {
    int slot = gid & 1023;
    int d = (gid >> 10) % BDEPTH;
    int i = gid / (BDEPTH * 1024);
    int n = 0;
#pragma unroll
    for (int b = 0; b < 10; ++b) {
      int src = b - d; if (src < 0) src += 10;
      n |= ((slot >> src) & 1) << b;
    }
    int pj = n & 511;
    float theta = bp[(i * HALF + pj) * BDEPTH + d];
    float c = cosf(theta), s = sinf(theta);
    float2 val = make_float2(c, (n & 512) ? -s : s);
    long base = (long)i * LSTRIDE;
    if (d < 4) {
      int r = slot >> 6, lane = slot & 63;
      int mr = 8 >> d;
      if ((r & mr) == 0) {                 // zero-slot: this one is stored
        int q;
        if (d == 0)      q = r;
        else if (d == 1) q = (r & 3) | ((r >> 3) << 2);
        else if (d == 2) q = ((r >> 2) << 1) | (r & 1);
        else             q = r >> 1;
        int tbl = d >> 1, sub = d & 1;
        cs[base + tbl * 1024 + (q * 64 + lane) * 2 + sub] = val;
      }
    } else {
      int p = (d - 4) >> 1, sub = (d - 4) & 1;
      cs[base + 2048 + p * 2048 + slot * 2 + sub] = val;
    }
  }
  int gid2 = gid - DEPTH * BDEPTH * 1024;
  if (gid2 >= 0 && gid2 < (DEPTH - 1) * NQ * HALF) {
    int w = gid2 & 511;
    int mi = (gid2 >> 9) % NQ;
    int i = gid2 / (NQ * HALF);
    int m = mi + 2;
    const float* cf = sc + (i * HALF + w) * SPLINE_DIM;
    double c0 = cf[mi], c1 = cf[mi + 1], c2 = cf[mi + 2];
    double tm1 = d_T[m - 1], tm = d_T[m], tp1 = d_T[m + 1], tp2 = d_T[m + 2];
    double h = tp1 - tm;
    double us[3] = { 0.0, 0.5 * h, 0.75 * h };
    double y[3];
#pragma unroll
    for (int k = 0; k < 3; ++k) {
      double x = tm + us[k];
      double left1 = x - tm, right1 = tp1 - x, left2 = x - tm1, right2 = tp2 - x;
      double inv1 = 1.0 / (tp1 - tm);
      double N0 = right1 * inv1, N1 = left1 * inv1;
      double temp0 = N0 / (tp1 - tm1);
      double B0 = right1 * temp0;
      double saved = left2 * temp0;
      double temp1 = N1 / (tp2 - tm);
      double B1 = right2 * temp1 + saved;
      double B2 = left1 * temp1;
      y[k] = c0 * B0 + c1 * B1 + c2 * B2;
    }
    double d1 = y[1] - y[0], d2 = y[2] - y[0];
    double u1 = us[1], u2 = us[2];
    double det = u1 * u2 * (u2 - u1);
    double Bq = (d1 * u2 * u2 - d2 * u1 * u1) / det;
    double Cq = (d2 * u1 - d1 * u2) / det;
    qt[gid2] = make_float4((float)y[0], (float)Bq, (float)Cq, (float)tm);
  }
}

// ---------------------------------------------------------------------------
// Lane shuffles (validated R17): DPP for 1,2,8; permlane swaps for 16,32;
// ds_swizzle only for 4.
// ---------------------------------------------------------------------------
template <int M>
__device__ __forceinline__ float shfx(float x, int lane) {
  if constexpr (M == 1)
    return __int_as_float(__builtin_amdgcn_mov_dpp(__float_as_int(x), 0xB1, 0xF, 0xF, true));
  else if constexpr (M == 2)
    return __int_as_float(__builtin_amdgcn_mov_dpp(__float_as_int(x), 0x4E, 0xF, 0xF, true));
  else if constexpr (M == 4)
    return __int_as_float(__builtin_amdgcn_ds_swizzle(__float_as_int(x), 0x101F));
  else if constexpr (M == 8)
    return __int_as_float(__builtin_amdgcn_mov_dpp(__float_as_int(x), 0x128, 0xF, 0xF, true));
  else if constexpr (M == 16) {
#if __has_builtin(__builtin_amdgcn_permlane16_swap)
    auto pr = __builtin_amdgcn_permlane16_swap(__float_as_uint(x), __float_as_uint(x), false, false);
    return __uint_as_float((lane & 16) ? pr[0] : pr[1]);
#else
    return __int_as_float(__builtin_amdgcn_ds_swizzle(__float_as_int(x), 0x401F));
#endif
  } else {
#if __has_builtin(__builtin_amdgcn_permlane32_swap)
    auto pr = __builtin_amdgcn_permlane32_swap(__float_as_uint(x), __float_as_uint(x), false, false);
    return __uint_as_float((lane & 32) ? pr[0] : pr[1]);
#else
    return __shfl_xor(x, 32, 64);
#endif
  }
}

// Quadratic spline activation (validated R3+).
__device__ __forceinline__ float qspline(float x, const float4* __restrict__ qL, int w) {
  x = fminf(fmaxf(x, -8.0f), 7.9999990f);
  float ax = fabsf(x);
  unsigned bits = __float_as_uint(ax);
  int e = (int)(bits >> 23) - 127;
  int ce = e + ((bits & 0x7fffffu) ? 1 : 0);
  int m = (x > 0.f) ? (17 + e) : (5 - ce);
  m = (ax < 0.03125f) ? ((x < 0.f) ? 10 : 11) : m;
  float4 qc = qL[(m - 2) * HALF + w];
  float u = x - qc.w;
  return fmaf(u, fmaf(u, qc.z, qc.y), qc.x);
}

typedef __attribute__((address_space(3))) unsigned int lds_u32;
typedef __attribute__((address_space(1))) const unsigned int glb_u32;

// Async-stage one full layer (64 KB) into LDS via global_load_lds (validated R17).
__device__ __forceinline__ void stage_async(const float2* __restrict__ src,
                                            float2* dst, int wv) {
#pragma unroll
  for (int k = 0; k < 8; ++k) {
    int seg = k * 8 + wv;
    const char* g = (const char*)src + seg * 1024 + (threadIdx.x & 63) * 16;
    char* l = (char*)dst + seg * 1024;
    __builtin_amdgcn_global_load_lds((glb_u32*)g, (lds_u32*)l, 16, 0, 0);
  }
}

// pair rotation on packed 2-row state (validated R17)
#define ROT(rz, rp, cc, ss) do {                                              \
    f32x2 _a = st[rz], _b = st[rp];                                           \
    f32x2 _vc = {cc, cc}, _vs = {ss, ss};                                     \
    st[rz] = __builtin_elementwise_fma(_a, _vc, _b * _vs);                    \
    st[rp] = __builtin_elementwise_fma(_b, _vc, -(_a * _vs));                 \
  } while (0)

// paired lane-steps from a REGISTER-staged table T (validated math, R17)
#define LPAIRR(T, M1, M2) do {                                                \
    _Pragma("unroll") for (int r = 0; r < 16; ++r) {                          \
      float4 v = T[r];                                                        \
      f32x2 q1 = { shfx<M1>(st[r].x, lane), shfx<M1>(st[r].y, lane) };        \
      st[r] = __builtin_elementwise_fma(st[r], (f32x2){v.x, v.x},             \
                                        q1 * (f32x2){v.y, v.y});              \
      f32x2 q2 = { shfx<M2>(st[r].x, lane), shfx<M2>(st[r].y, lane) };        \
      st[r] = __builtin_elementwise_fma(st[r], (f32x2){v.z, v.z},             \
                                        q2 * (f32x2){v.w, v.w});              \
    }                                                                         \
  } while (0)

// ---------------------------------------------------------------------------
// Main kernel (R17 structure + register-staged tables with sched_barrier(0)
// pins; R18's concept with the LP1/LP2 base addresses CORRECTED to the
// validated R17 float4 offsets 2048/3072):
//   post-barrier: issue tbl0+tbl1 (16 b128) + LP0 (16 b128) | pin
//   steps 0-3 (V01)  + issue LP1 (16 b128)                  | pin
//   LPAIR(LP0)       + issue LP2 (16 b128)                  | pin
//   LPAIR(LP1), LPAIR(LP2), spline
// LDS pins 8 waves/CU (2/SIMD) regardless, so ~256 VGPRs are free budget.
// ---------------------------------------------------------------------------
__global__ __launch_bounds__(512, 1) void fwd_kernel(
    const float* __restrict__ X, const float2* __restrict__ cs,
    const float4* __restrict__ qt, float* __restrict__ out) {
  __shared__ float2 bufA[LSTRIDE];   // 64 KB
  __shared__ float2 bufB[LSTRIDE];   // 64 KB
  int tid = threadIdx.x;
  int lane = tid & 63;
  int wv = tid >> 6;                       // 0..7
  int row0 = blockIdx.x * 16 + wv * 2;

  const float* x0p = X + (long)row0 * NIN;
  const float* x1p = X + (long)(row0 + 1) * NIN;
  f32x2 st[16];
#pragma unroll
  for (int r = 0; r < 16; ++r) {
    int w = r * 64 + lane;
    bool in = (w < NIN);
    st[r] = (f32x2){ in ? x0p[w] : 0.f, in ? x1p[w] : 0.f };
  }

  // prologue: start DMA of layer 0 into bufA
  stage_async(cs, bufA, wv);

#pragma unroll 1
  for (int i = 0; i < DEPTH; ++i) {
    const float2* cur = (i & 1) ? bufB : bufA;
    float2* nxt = (i & 1) ? bufA : bufB;

    __syncthreads();                       // nxt fully consumed (prev layer)
    stage_async(cs + ((i + 1) & 7) * LSTRIDE, nxt, wv);  // next layer (i=7: dummy)
    asm volatile("s_waitcnt vmcnt(8)" ::: "memory");     // cur's 8 DMAs done
    __syncthreads();                       // all waves' cur DMAs landed

    // ---- batch-issue steps 0-3 tables (16 b128) + LP0 (16 b128)
    const float4* cp = (const float4*)cur;   // tbl0 f4[0..512), tbl1 f4[512..1024)
    float4 V01[16], T0[16];
#pragma unroll
    for (int q = 0; q < 16; ++q) V01[q] = cp[q * 64 + lane];   // q<8: tbl0, q>=8: tbl1
#pragma unroll
    for (int r = 0; r < 16; ++r) T0[r] = cp[1024 + r * 64 + lane];      // LP0
    __builtin_amdgcn_sched_barrier(0);

    // ---- steps 0,1 (V01[0..7])
#pragma unroll
    for (int q = 0; q < 8; ++q) ROT(q, q + 8, V01[q].x, V01[q].y);
#pragma unroll
    for (int q = 0; q < 8; ++q) {
      const int rz = (q < 4) ? q : q + 4;
      ROT(rz, rz + 4, V01[q].z, V01[q].w);
    }
    // ---- steps 2,3 (V01[8..15])
#pragma unroll
    for (int q = 0; q < 8; ++q) {
      const int rz = ((q >> 1) << 2) | (q & 1);
      ROT(rz, rz + 2, V01[8 + q].x, V01[8 + q].y);
    }
#pragma unroll
    for (int q = 0; q < 8; ++q) {
      const int rz = 2 * q;
      ROT(rz, rz + 1, V01[8 + q].z, V01[8 + q].w);
    }
    // issue LP1 while steps 0-3 retire
    float4 T1[16];
#pragma unroll
    for (int r = 0; r < 16; ++r) T1[r] = cp[2048 + r * 64 + lane];      // LP1
    __builtin_amdgcn_sched_barrier(0);

    // ---- steps 4,5 from T0; issue LP2
    LPAIRR(T0, 32, 16);
    float4 T2[16];
#pragma unroll
    for (int r = 0; r < 16; ++r) T2[r] = cp[3072 + r * 64 + lane];      // LP2
    __builtin_amdgcn_sched_barrier(0);

    // ---- steps 6,7 and 8,9
    LPAIRR(T1, 8, 4);
    LPAIRR(T2, 2, 1);

    if (i != DEPTH - 1) {
      const float4* qL = qt + i * (NQ * HALF);
#pragma unroll
      for (int r = 8; r < 16; ++r) {
        int w = ((r - 8) << 6) | lane;
        st[r - 8].x += qspline(st[r].x, qL, w);
        st[r - 8].y += qspline(st[r].y, qL, w);
      }
    }
  }

  float* o0 = out + (long)row0 * NIN;
  float* o1 = out + (long)(row0 + 1) * NIN;
#pragma unroll
  for (int r = 0; r < 13; ++r) {
    int w = r * 64 + lane;
    if (w < NIN) { o0[w] = st[r].x; o1[w] = st[r].y; }
  }
}

extern "C" void kernel_launch(void* const* d_in, const int* in_sizes, int n_in,
                              void* d_out, int out_size, void* d_ws, size_t ws_size,
                              hipStream_t stream) {
  const float* X  = (const float*)d_in[0];
  const float* bp = (const float*)d_in[1];   // [8,512,10]
  const float* sc = (const float*)d_in[2];   // [7,512,20]
  float* out = (float*)d_out;

  float2* cs = (float2*)d_ws;                                   // 524,288 B
  float4* qt = (float4*)((char*)d_ws + DEPTH * LSTRIDE * sizeof(float2)); // 1,032,192 B

  int prep_threads = DEPTH * BDEPTH * 1024 + (DEPTH - 1) * NQ * HALF; // 146,432
  prep_kernel<<<(prep_threads + 255) / 256, 256, 0, stream>>>(bp, sc, cs, qt);
  fwd_kernel<<<BATCH / 16, 512, 0, stream>>>(X, cs, qt, out);
}

// Round 20
// 59.868 us; speedup vs baseline: 1.0367x; 1.0367x over previous
//
#include <hip/hip_runtime.h>

#define NIN 784
#define WIDTH 1024
#define HALF 512
#define DEPTH 8
#define BDEPTH 10
#define BATCH 4096
#define SPLINE_DIM 20
#define NQ 18   // knot intervals [t_m, t_m+1), m = 2..19
#define LSTRIDE 8192   // float2 per layer table (64 KB)

typedef __attribute__((ext_vector_type(2))) float f32x2;

// Clamped knot vector T[23]: [-8]*3, +-2^k/32 ladder, 0, [8]*3
__device__ float d_T[23] = {
  -8.f, -8.f, -8.f, -4.f, -2.f, -1.f, -0.5f, -0.25f, -0.125f, -0.0625f,
  -0.03125f, 0.f, 0.03125f, 0.0625f, 0.125f, 0.25f, 0.5f, 1.f, 2.f, 4.f,
  8.f, 8.f, 8.f };

// ---------------------------------------------------------------------------
// Prep kernel (IDENTICAL to validated R17/R19). cs layout per layer (8192 f2):
//   tbl0 [0,1024):    float4[512]  steps 0,1 packed
//   tbl1 [1024,2048): float4[512]  steps 2,3 packed
//   LP p [2048+p*2048): float4[1024] steps 4+2p,5+2p per slot
// qt quadratic spline unchanged (validated R3+).
// ---------------------------------------------------------------------------
__global__ void prep_kernel(const float* __restrict__ bp,
                            const float* __restrict__ sc,
                            float2* __restrict__ cs,
                            float4* __restrict__ qt) {
  int gid = blockIdx.x * 256 + threadIdx.x;
  if (gid < DEPTH * BDEPTH * 1024) {
    int slot = gid & 1023;
    int d = (gid >> 10) % BDEPTH;
    int i = gid / (BDEPTH * 1024);
    int n = 0;
#pragma unroll
    for (int b = 0; b < 10; ++b) {
      int src = b - d; if (src < 0) src += 10;
      n |= ((slot >> src) & 1) << b;
    }
    int pj = n & 511;
    float theta = bp[(i * HALF + pj) * BDEPTH + d];
    float c = cosf(theta), s = sinf(theta);
    float2 val = make_float2(c, (n & 512) ? -s : s);
    long base = (long)i * LSTRIDE;
    if (d < 4) {
      int r = slot >> 6, lane = slot & 63;
      int mr = 8 >> d;
      if ((r & mr) == 0) {                 // zero-slot: this one is stored
        int q;
        if (d == 0)      q = r;
        else if (d == 1) q = (r & 3) | ((r >> 3) << 2);
        else if (d == 2) q = ((r >> 2) << 1) | (r & 1);
        else             q = r >> 1;
        int tbl = d >> 1, sub = d & 1;
        cs[base + tbl * 1024 + (q * 64 + lane) * 2 + sub] = val;
      }
    } else {
      int p = (d - 4) >> 1, sub = (d - 4) & 1;
      cs[base + 2048 + p * 2048 + slot * 2 + sub] = val;
    }
  }
  int gid2 = gid - DEPTH * BDEPTH * 1024;
  if (gid2 >= 0 && gid2 < (DEPTH - 1) * NQ * HALF) {
    int w = gid2 & 511;
    int mi = (gid2 >> 9) % NQ;
    int i = gid2 / (NQ * HALF);
    int m = mi + 2;
    const float* cf = sc + (i * HALF + w) * SPLINE_DIM;
    double c0 = cf[mi], c1 = cf[mi + 1], c2 = cf[mi + 2];
    double tm1 = d_T[m - 1], tm = d_T[m], tp1 = d_T[m + 1], tp2 = d_T[m + 2];
    double h = tp1 - tm;
    double us[3] = { 0.0, 0.5 * h, 0.75 * h };
    double y[3];
#pragma unroll
    for (int k = 0; k < 3; ++k) {
      double x = tm + us[k];
      double left1 = x - tm, right1 = tp1 - x, left2 = x - tm1, right2 = tp2 - x;
      double inv1 = 1.0 / (tp1 - tm);
      double N0 = right1 * inv1, N1 = left1 * inv1;
      double temp0 = N0 / (tp1 - tm1);
      double B0 = right1 * temp0;
      double saved = left2 * temp0;
      double temp1 = N1 / (tp2 - tm);
      double B1 = right2 * temp1 + saved;
      double B2 = left1 * temp1;
      y[k] = c0 * B0 + c1 * B1 + c2 * B2;
    }
    double d1 = y[1] - y[0], d2 = y[2] - y[0];
    double u1 = us[1], u2 = us[2];
    double det = u1 * u2 * (u2 - u1);
    double Bq = (d1 * u2 * u2 - d2 * u1 * u1) / det;
    double Cq = (d2 * u1 - d1 * u2) / det;
    qt[gid2] = make_float4((float)y[0], (float)Bq, (float)Cq, (float)tm);
  }
}

// ---------------------------------------------------------------------------
// Lane shuffles (validated R17): DPP for 1,2,8; permlane swaps for 16,32;
// ds_swizzle only for 4.
// ---------------------------------------------------------------------------
template <int M>
__device__ __forceinline__ float shfx(float x, int lane) {
  if constexpr (M == 1)
    return __int_as_float(__builtin_amdgcn_mov_dpp(__float_as_int(x), 0xB1, 0xF, 0xF, true));
  else if constexpr (M == 2)
    return __int_as_float(__builtin_amdgcn_mov_dpp(__float_as_int(x), 0x4E, 0xF, 0xF, true));
  else if constexpr (M == 4)
    return __int_as_float(__builtin_amdgcn_ds_swizzle(__float_as_int(x), 0x101F));
  else if constexpr (M == 8)
    return __int_as_float(__builtin_amdgcn_mov_dpp(__float_as_int(x), 0x128, 0xF, 0xF, true));
  else if constexpr (M == 16) {
#if __has_builtin(__builtin_amdgcn_permlane16_swap)
    auto pr = __builtin_amdgcn_permlane16_swap(__float_as_uint(x), __float_as_uint(x), false, false);
    return __uint_as_float((lane & 16) ? pr[0] : pr[1]);
#else
    return __int_as_float(__builtin_amdgcn_ds_swizzle(__float_as_int(x), 0x401F));
#endif
  } else {
#if __has_builtin(__builtin_amdgcn_permlane32_swap)
    auto pr = __builtin_amdgcn_permlane32_swap(__float_as_uint(x), __float_as_uint(x), false, false);
    return __uint_as_float((lane & 32) ? pr[0] : pr[1]);
#else
    return __shfl_xor(x, 32, 64);
#endif
  }
}

// Quadratic spline activation (validated R3+).
__device__ __forceinline__ float qspline(float x, const float4* __restrict__ qL, int w) {
  x = fminf(fmaxf(x, -8.0f), 7.9999990f);
  float ax = fabsf(x);
  unsigned bits = __float_as_uint(ax);
  int e = (int)(bits >> 23) - 127;
  int ce = e + ((bits & 0x7fffffu) ? 1 : 0);
  int m = (x > 0.f) ? (17 + e) : (5 - ce);
  m = (ax < 0.03125f) ? ((x < 0.f) ? 10 : 11) : m;
  float4 qc = qL[(m - 2) * HALF + w];
  float u = x - qc.w;
  return fmaf(u, fmaf(u, qc.z, qc.y), qc.x);
}

typedef __attribute__((address_space(3))) unsigned int lds_u32;
typedef __attribute__((address_space(1))) const unsigned int glb_u32;

// Stage one full layer (64 KB) into LDS via global_load_lds. 64 wave-segments
// of 1 KB; wave wv (0..3) takes segs {k*4+wv}, k=0..15 -> 16 DMAs/wave.
__device__ __forceinline__ void stage_issue(const float2* __restrict__ src,
                                            float2* dst, int wv) {
#pragma unroll
  for (int k = 0; k < 16; ++k) {
    int seg = k * 4 + wv;
    const char* g = (const char*)src + seg * 1024 + (threadIdx.x & 63) * 16;
    char* l = (char*)dst + seg * 1024;
    __builtin_amdgcn_global_load_lds((glb_u32*)g, (lds_u32*)l, 16, 0, 0);
  }
}

// pair rotation on packed 2-row state (validated R17)
#define ROT(rz, rp, cc, ss) do {                                              \
    f32x2 _a = st[rz], _b = st[rp];                                           \
    f32x2 _vc = {cc, cc}, _vs = {ss, ss};                                     \
    st[rz] = __builtin_elementwise_fma(_a, _vc, _b * _vs);                    \
    st[rp] = __builtin_elementwise_fma(_b, _vc, -(_a * _vs));                 \
  } while (0)

// paired lane-steps: one b128 feeds steps (mask M1) then (mask M2) (validated R17)
#define LPAIR(p, M1, M2) do {                                                 \
    const float4* _pp = (const float4*)(cur + 2048 + (p) * 2048);             \
    _Pragma("unroll") for (int r = 0; r < 16; ++r) {                          \
      float4 v = _pp[r * 64 + lane];                                          \
      f32x2 q1 = { shfx<M1>(st[r].x, lane), shfx<M1>(st[r].y, lane) };        \
      st[r] = __builtin_elementwise_fma(st[r], (f32x2){v.x, v.x},             \
                                        q1 * (f32x2){v.y, v.y});              \
      f32x2 q2 = { shfx<M2>(st[r].x, lane), shfx<M2>(st[r].y, lane) };        \
      st[r] = __builtin_elementwise_fma(st[r], (f32x2){v.z, v.z},             \
                                        q2 * (f32x2){v.w, v.w});              \
    }                                                                         \
  } while (0)

// ---------------------------------------------------------------------------
// Main kernel: 512 blocks x 256 threads (4 waves, 8 rows), TWO INDEPENDENT
// BLOCKS PER CU. Each block single-buffers the 64 KB layer table (128 KB/CU)
// and stages it synchronously (vmcnt(0)); while one block drains its burst,
// the other block's 4 waves compute -- cross-block overlap replaces R17's
// intra-block async. This breaks the single 8-wave barrier group that R17/R19
// counters implicated (every wave stalled at the same convergence points).
// Compute body byte-identical to validated R17 (DS-diet + pk-math).
// ---------------------------------------------------------------------------
__global__ __launch_bounds__(256, 2) void fwd_kernel(
    const float* __restrict__ X, const float2* __restrict__ cs,
    const float4* __restrict__ qt, float* __restrict__ out) {
  __shared__ float2 buf[LSTRIDE];   // 64 KB, single-buffered
  int tid = threadIdx.x;
  int lane = tid & 63;
  int wv = tid >> 6;                       // 0..3
  int row0 = blockIdx.x * 8 + wv * 2;

  const float* x0p = X + (long)row0 * NIN;
  const float* x1p = X + (long)(row0 + 1) * NIN;
  f32x2 st[16];
#pragma unroll
  for (int r = 0; r < 16; ++r) {
    int w = r * 64 + lane;
    bool in = (w < NIN);
    st[r] = (f32x2){ in ? x0p[w] : 0.f, in ? x1p[w] : 0.f };
  }

#pragma unroll 1
  for (int i = 0; i < DEPTH; ++i) {
    const float2* cur = buf;

    __syncthreads();                       // prev layer's reads done
    stage_issue(cs + (long)i * LSTRIDE, buf, wv);
    asm volatile("s_waitcnt vmcnt(0)" ::: "memory");   // this block's DMAs done
    __syncthreads();                       // all 4 waves' segments landed

    // ---- steps 0,1 from tbl0
    {
      const float4* cp = (const float4*)cur;
      float4 V[8];
#pragma unroll
      for (int q = 0; q < 8; ++q) V[q] = cp[q * 64 + lane];
#pragma unroll
      for (int q = 0; q < 8; ++q) ROT(q, q + 8, V[q].x, V[q].y);
#pragma unroll
      for (int q = 0; q < 8; ++q) {
        const int rz = (q < 4) ? q : q + 4;
        ROT(rz, rz + 4, V[q].z, V[q].w);
      }
    }
    // ---- steps 2,3 from tbl1
    {
      const float4* cp = (const float4*)(cur + 1024);
      float4 V[8];
#pragma unroll
      for (int q = 0; q < 8; ++q) V[q] = cp[q * 64 + lane];
#pragma unroll
      for (int q = 0; q < 8; ++q) {
        const int rz = ((q >> 1) << 2) | (q & 1);
        ROT(rz, rz + 2, V[q].x, V[q].y);
      }
#pragma unroll
      for (int q = 0; q < 8; ++q) {
        const int rz = 2 * q;
        ROT(rz, rz + 1, V[q].z, V[q].w);
      }
    }
    // ---- steps 4-9
    LPAIR(0, 32, 16);
    LPAIR(1, 8, 4);
    LPAIR(2, 2, 1);

    if (i != DEPTH - 1) {
      const float4* qL = qt + i * (NQ * HALF);
#pragma unroll
      for (int r = 8; r < 16; ++r) {
        int w = ((r - 8) << 6) | lane;
        st[r - 8].x += qspline(st[r].x, qL, w);
        st[r - 8].y += qspline(st[r].y, qL, w);
      }
    }
  }

  float* o0 = out + (long)row0 * NIN;
  float* o1 = out + (long)(row0 + 1) * NIN;
#pragma unroll
  for (int r = 0; r < 13; ++r) {
    int w = r * 64 + lane;
    if (w < NIN) { o0[w] = st[r].x; o1[w] = st[r].y; }
  }
}

extern "C" void kernel_launch(void* const* d_in, const int* in_sizes, int n_in,
                              void* d_out, int out_size, void* d_ws, size_t ws_size,
                              hipStream_t stream) {
  const float* X  = (const float*)d_in[0];
  const float* bp = (const float*)d_in[1];   // [8,512,10]
  const float* sc = (const float*)d_in[2];   // [7,512,20]
  float* out = (float*)d_out;

  float2* cs = (float2*)d_ws;                                   // 524,288 B
  float4* qt = (float4*)((char*)d_ws + DEPTH * LSTRIDE * sizeof(float2)); // 1,032,192 B

  int prep_threads = DEPTH * BDEPTH * 1024 + (DEPTH - 1) * NQ * HALF; // 146,432
  prep_kernel<<<(prep_threads + 255) / 256, 256, 0, stream>>>(bp, sc, cs, qt);
  fwd_kernel<<<BATCH / 8, 256, 0, stream>>>(X, cs, qt, out);
}

// Round 21
// 59.623 us; speedup vs baseline: 1.0410x; 1.0041x over previous
//
#include <hip/hip_runtime.h>

#define NIN 784
#define WIDTH 1024
#define HALF 512
#define DEPTH 8
#define BDEPTH 10
#define BATCH 4096
#define SPLINE_DIM 20
#define NQ 18   // knot intervals [t_m, t_m+1), m = 2..19
#define LSTRIDE 8192   // float2 per layer table (64 KB)

typedef __attribute__((ext_vector_type(2))) float f32x2;

// Clamped knot vector T[23]: [-8]*3, +-2^k/32 ladder, 0, [8]*3
__device__ float d_T[23] = {
  -8.f, -8.f, -8.f, -4.f, -2.f, -1.f, -0.5f, -0.25f, -0.125f, -0.0625f,
  -0.03125f, 0.f, 0.03125f, 0.0625f, 0.125f, 0.25f, 0.5f, 1.f, 2.f, 4.f,
  8.f, 8.f, 8.f };

// ---------------------------------------------------------------------------
// Prep kernel (IDENTICAL to validated R17-R20). cs layout per layer (8192 f2):
//   tbl0 [0,1024):    float4[512]  steps 0,1 packed
//   tbl1 [1024,2048): float4[512]  steps 2,3 packed
//   LP p [2048+p*2048): float4[1024] steps 4+2p,5+2p per slot
// qt quadratic spline unchanged (validated R3+).
// ---------------------------------------------------------------------------
__global__ void prep_kernel(const float* __restrict__ bp,
                            const float* __restrict__ sc,
                            float2* __restrict__ cs,
                            float4* __restrict__ qt) {
  int gid = blockIdx.x * 256 + threadIdx.x;
  if (gid < DEPTH * BDEPTH * 1024) {
    int slot = gid & 1023;
    int d = (gid >> 10) % BDEPTH;
    int i = gid / (BDEPTH * 1024);
    int n = 0;
#pragma unroll
    for (int b = 0; b < 10; ++b) {
      int src = b - d; if (src < 0) src += 10;
      n |= ((slot >> src) & 1) << b;
    }
    int pj = n & 511;
    float theta = bp[(i * HALF + pj) * BDEPTH + d];
    float c = cosf(theta), s = sinf(theta);
    float2 val = make_float2(c, (n & 512) ? -s : s);
    long base = (long)i * LSTRIDE;
    if (d < 4) {
      int r = slot >> 6, lane = slot & 63;
      int mr = 8 >> d;
      if ((r & mr) == 0) {                 // zero-slot: this one is stored
        int q;
        if (d == 0)      q = r;
        else if (d == 1) q = (r & 3) | ((r >> 3) << 2);
        else if (d == 2) q = ((r >> 2) << 1) | (r & 1);
        else             q = r >> 1;
        int tbl = d >> 1, sub = d & 1;
        cs[base + tbl * 1024 + (q * 64 + lane) * 2 + sub] = val;
      }
    } else {
      int p = (d - 4) >> 1, sub = (d - 4) & 1;
      cs[base + 2048 + p * 2048 + slot * 2 + sub] = val;
    }
  }
  int gid2 = gid - DEPTH * BDEPTH * 1024;
  if (gid2 >= 0 && gid2 < (DEPTH - 1) * NQ * HALF) {
    int w = gid2 & 511;
    int mi = (gid2 >> 9) % NQ;
    int i = gid2 / (NQ * HALF);
    int m = mi + 2;
    const float* cf = sc + (i * HALF + w) * SPLINE_DIM;
    double c0 = cf[mi], c1 = cf[mi + 1], c2 = cf[mi + 2];
    double tm1 = d_T[m - 1], tm = d_T[m], tp1 = d_T[m + 1], tp2 = d_T[m + 2];
    double h = tp1 - tm;
    double us[3] = { 0.0, 0.5 * h, 0.75 * h };
    double y[3];
#pragma unroll
    for (int k = 0; k < 3; ++k) {
      double x = tm + us[k];
      double left1 = x - tm, right1 = tp1 - x, left2 = x - tm1, right2 = tp2 - x;
      double inv1 = 1.0 / (tp1 - tm);
      double N0 = right1 * inv1, N1 = left1 * inv1;
      double temp0 = N0 / (tp1 - tm1);
      double B0 = right1 * temp0;
      double saved = left2 * temp0;
      double temp1 = N1 / (tp2 - tm);
      double B1 = right2 * temp1 + saved;
      double B2 = left1 * temp1;
      y[k] = c0 * B0 + c1 * B1 + c2 * B2;
    }
    double d1 = y[1] - y[0], d2 = y[2] - y[0];
    double u1 = us[1], u2 = us[2];
    double det = u1 * u2 * (u2 - u1);
    double Bq = (d1 * u2 * u2 - d2 * u1 * u1) / det;
    double Cq = (d2 * u1 - d1 * u2) / det;
    qt[gid2] = make_float4((float)y[0], (float)Bq, (float)Cq, (float)tm);
  }
}

// ---------------------------------------------------------------------------
// Lane shuffles (validated R17): DPP for 1,2,8; permlane swaps for 16,32;
// ds_swizzle only for 4.
// ---------------------------------------------------------------------------
template <int M>
__device__ __forceinline__ float shfx(float x, int lane) {
  if constexpr (M == 1)
    return __int_as_float(__builtin_amdgcn_mov_dpp(__float_as_int(x), 0xB1, 0xF, 0xF, true));
  else if constexpr (M == 2)
    return __int_as_float(__builtin_amdgcn_mov_dpp(__float_as_int(x), 0x4E, 0xF, 0xF, true));
  else if constexpr (M == 4)
    return __int_as_float(__builtin_amdgcn_ds_swizzle(__float_as_int(x), 0x101F));
  else if constexpr (M == 8)
    return __int_as_float(__builtin_amdgcn_mov_dpp(__float_as_int(x), 0x128, 0xF, 0xF, true));
  else if constexpr (M == 16) {
#if __has_builtin(__builtin_amdgcn_permlane16_swap)
    auto pr = __builtin_amdgcn_permlane16_swap(__float_as_uint(x), __float_as_uint(x), false, false);
    return __uint_as_float((lane & 16) ? pr[0] : pr[1]);
#else
    return __int_as_float(__builtin_amdgcn_ds_swizzle(__float_as_int(x), 0x401F));
#endif
  } else {
#if __has_builtin(__builtin_amdgcn_permlane32_swap)
    auto pr = __builtin_amdgcn_permlane32_swap(__float_as_uint(x), __float_as_uint(x), false, false);
    return __uint_as_float((lane & 32) ? pr[0] : pr[1]);
#else
    return __shfl_xor(x, 32, 64);
#endif
  }
}

// Quadratic spline activation (validated R3+).
__device__ __forceinline__ float qspline(float x, const float4* __restrict__ qL, int w) {
  x = fminf(fmaxf(x, -8.0f), 7.9999990f);
  float ax = fabsf(x);
  unsigned bits = __float_as_uint(ax);
  int e = (int)(bits >> 23) - 127;
  int ce = e + ((bits & 0x7fffffu) ? 1 : 0);
  int m = (x > 0.f) ? (17 + e) : (5 - ce);
  m = (ax < 0.03125f) ? ((x < 0.f) ? 10 : 11) : m;
  float4 qc = qL[(m - 2) * HALF + w];
  float u = x - qc.w;
  return fmaf(u, fmaf(u, qc.z, qc.y), qc.x);
}

typedef __attribute__((address_space(3))) unsigned int lds_u32;
typedef __attribute__((address_space(1))) const unsigned int glb_u32;

// Stage one full layer (64 KB) into LDS via global_load_lds (validated R20).
__device__ __forceinline__ void stage_issue(const float2* __restrict__ src,
                                            float2* dst, int wv) {
#pragma unroll
  for (int k = 0; k < 16; ++k) {
    int seg = k * 4 + wv;
    const char* g = (const char*)src + seg * 1024 + (threadIdx.x & 63) * 16;
    char* l = (char*)dst + seg * 1024;
    __builtin_amdgcn_global_load_lds((glb_u32*)g, (lds_u32*)l, 16, 0, 0);
  }
}

// ---------------------------------------------------------------------------
// Forced VOP3P packed-fp32 with op_sel broadcasts (zero-mov coefficient
// broadcast from a (c,s) pair held as one 64-bit vreg pair):
//   PK_MUL_BH:  d = a * b.y (sin broadcast)
//   PK_FMA_BL:  d = a * b.x (cos broadcast) + c
//   PK_FMA_BL_NC: d = a * b.x - c
// ---------------------------------------------------------------------------
#define PK_MUL_BH(d, a, b)                                                    \
  asm("v_pk_mul_f32 %0, %1, %2 op_sel:[0,1] op_sel_hi:[1,1]"                  \
      : "=v"(d) : "v"(a), "v"(b))
#define PK_FMA_BL(d, a, b, c)                                                 \
  asm("v_pk_fma_f32 %0, %1, %2, %3 op_sel:[0,0,0] op_sel_hi:[1,0,1]"          \
      : "=v"(d) : "v"(a), "v"(b), "v"(c))
#define PK_FMA_BL_NC(d, a, b, c)                                              \
  asm("v_pk_fma_f32 %0, %1, %2, %3 op_sel:[0,0,0] op_sel_hi:[1,0,1] "         \
      "neg_lo:[0,0,1] neg_hi:[0,0,1]"                                         \
      : "=v"(d) : "v"(a), "v"(b), "v"(c))

union F4 { float4 f; f32x2 h[2]; };

// pair rotation on packed 2-row state, coefficients (c,s) in csp (f32x2):
//   st[rz] = a*c + b*s ; st[rp] = b*c - a*s       (4 pk ops, 0 movs)
#define ROT(rz, rp, csp) do {                                                 \
    f32x2 _t1, _t2;                                                           \
    PK_MUL_BH(_t1, st[rp], csp);          /* b*s */                           \
    PK_MUL_BH(_t2, st[rz], csp);          /* a*s */                           \
    PK_FMA_BL(st[rz], st[rz], csp, _t1);  /* a*c + b*s */                     \
    PK_FMA_BL_NC(st[rp], st[rp], csp, _t2); /* b*c - a*s */                   \
  } while (0)

// one lane-step on st[r] with mask M, coefficients csp: st = st*c + shf(st)*s
#define LSTEP1(r, M, csp) do {                                                \
    f32x2 _q = { shfx<M>(st[r].x, lane), shfx<M>(st[r].y, lane) };            \
    f32x2 _t;                                                                 \
    PK_MUL_BH(_t, _q, csp);                                                   \
    PK_FMA_BL(st[r], st[r], csp, _t);                                         \
  } while (0)

// paired lane-steps: one b128 feeds steps (mask M1) then (mask M2)
#define LPAIR(p, M1, M2) do {                                                 \
    const float4* _pp = (const float4*)(cur + 2048 + (p) * 2048);             \
    _Pragma("unroll") for (int r = 0; r < 16; ++r) {                          \
      F4 v; v.f = _pp[r * 64 + lane];                                         \
      LSTEP1(r, M1, v.h[0]);                                                  \
      LSTEP1(r, M2, v.h[1]);                                                  \
    }                                                                         \
  } while (0)

// ---------------------------------------------------------------------------
// Main kernel (R20 structure, byte-identical dataflow; one change): all
// butterfly arithmetic forced to v_pk_mul_f32/v_pk_fma_f32 via inline asm.
// R20's VALUBusy arithmetic (8.7k cyc/SIMD/layer = 2x the packed instruction
// count) showed the compiler scalarized the f32x2 ops; this halves the
// butterfly VALU work with op_sel broadcasts costing zero movs.
// ---------------------------------------------------------------------------
__global__ __launch_bounds__(256, 2) void fwd_kernel(
    const float* __restrict__ X, const float2* __restrict__ cs,
    const float4* __restrict__ qt, float* __restrict__ out) {
  __shared__ float2 buf[LSTRIDE];   // 64 KB, single-buffered
  int tid = threadIdx.x;
  int lane = tid & 63;
  int wv = tid >> 6;                       // 0..3
  int row0 = blockIdx.x * 8 + wv * 2;

  const float* x0p = X + (long)row0 * NIN;
  const float* x1p = X + (long)(row0 + 1) * NIN;
  f32x2 st[16];
#pragma unroll
  for (int r = 0; r < 16; ++r) {
    int w = r * 64 + lane;
    bool in = (w < NIN);
    st[r] = (f32x2){ in ? x0p[w] : 0.f, in ? x1p[w] : 0.f };
  }

#pragma unroll 1
  for (int i = 0; i < DEPTH; ++i) {
    const float2* cur = buf;

    __syncthreads();                       // prev layer's reads done
    stage_issue(cs + (long)i * LSTRIDE, buf, wv);
    asm volatile("s_waitcnt vmcnt(0)" ::: "memory");   // this block's DMAs done
    __syncthreads();                       // all 4 waves' segments landed

    // ---- steps 0,1 from tbl0
    {
      const float4* cp = (const float4*)cur;
      F4 V[8];
#pragma unroll
      for (int q = 0; q < 8; ++q) V[q].f = cp[q * 64 + lane];
#pragma unroll
      for (int q = 0; q < 8; ++q) ROT(q, q + 8, V[q].h[0]);
#pragma unroll
      for (int q = 0; q < 8; ++q) {
        const int rz = (q < 4) ? q : q + 4;
        ROT(rz, rz + 4, V[q].h[1]);
      }
    }
    // ---- steps 2,3 from tbl1
    {
      const float4* cp = (const float4*)(cur + 1024);
      F4 V[8];
#pragma unroll
      for (int q = 0; q < 8; ++q) V[q].f = cp[q * 64 + lane];
#pragma unroll
      for (int q = 0; q < 8; ++q) {
        const int rz = ((q >> 1) << 2) | (q & 1);
        ROT(rz, rz + 2, V[q].h[0]);
      }
#pragma unroll
      for (int q = 0; q < 8; ++q) {
        const int rz = 2 * q;
        ROT(rz, rz + 1, V[q].h[1]);
      }
    }
    // ---- steps 4-9
    LPAIR(0, 32, 16);
    LPAIR(1, 8, 4);
    LPAIR(2, 2, 1);

    if (i != DEPTH - 1) {
      const float4* qL = qt + i * (NQ * HALF);
#pragma unroll
      for (int r = 8; r < 16; ++r) {
        int w = ((r - 8) << 6) | lane;
        st[r - 8].x += qspline(st[r].x, qL, w);
        st[r - 8].y += qspline(st[r].y, qL, w);
      }
    }
  }

  float* o0 = out + (long)row0 * NIN;
  float* o1 = out + (long)(row0 + 1) * NIN;
#pragma unroll
  for (int r = 0; r < 13; ++r) {
    int w = r * 64 + lane;
    if (w < NIN) { o0[w] = st[r].x; o1[w] = st[r].y; }
  }
}

extern "C" void kernel_launch(void* const* d_in, const int* in_sizes, int n_in,
                              void* d_out, int out_size, void* d_ws, size_t ws_size,
                              hipStream_t stream) {
  const float* X  = (const float*)d_in[0];
  const float* bp = (const float*)d_in[1];   // [8,512,10]
  const float* sc = (const float*)d_in[2];   // [7,512,20]
  float* out = (float*)d_out;

  float2* cs = (float2*)d_ws;                                   // 524,288 B
  float4* qt = (float4*)((char*)d_ws + DEPTH * LSTRIDE * sizeof(float2)); // 1,032,192 B

  int prep_threads = DEPTH * BDEPTH * 1024 + (DEPTH - 1) * NQ * HALF; // 146,432
  prep_kernel<<<(prep_threads + 255) / 256, 256, 0, stream>>>(bp, sc, cs, qt);
  fwd_kernel<<<BATCH / 8, 256, 0, stream>>>(X, cs, qt, out);
}